// Round 1
// baseline (741.505 us; speedup 1.0000x reference)
//
#include <hip/hip_runtime.h>
#include <hip/hip_bf16.h>

#define LDIM 4096
#define FDIM 64
#define BM 64
#define BK 64
#define NIT (LDIM / BK)   // 64

typedef __attribute__((ext_vector_type(8))) __bf16 bf16x8;
typedef __attribute__((ext_vector_type(4))) float f32x4;

__device__ __forceinline__ unsigned short f2bf(float f) {
    unsigned int u = __float_as_uint(f);
    u += 0x7fffu + ((u >> 16) & 1u);       // round-to-nearest-even
    return (unsigned short)(u >> 16);
}

// Kernel 1: hiddenT[b][o][l] = sum_f text[b][l][f] * weight[f][o], stored bf16 (bits)
// Transposed layout so kernel 2's B-fragment reads are contiguous in k.
__global__ __launch_bounds__(256) void hidden_kernel(
    const float* __restrict__ text, const float* __restrict__ weight,
    unsigned short* __restrict__ hT)
{
    const int b  = blockIdx.x & 7;
    const int lc = blockIdx.x >> 3;        // 0..63
    const int l0 = lc * 64;
    __shared__ float sw[64 * 64];          // weight [f][o]
    __shared__ float st[64 * 65];          // text tile [l][f], +1 pad
    const int t = threadIdx.x;
    #pragma unroll
    for (int i = 0; i < 16; ++i) sw[t + i * 256] = weight[t + i * 256];
    const float* tp = text + ((size_t)b * LDIM + l0) * FDIM;
    #pragma unroll
    for (int i = 0; i < 16; ++i) {
        int idx = t + i * 256;
        st[(idx >> 6) * 65 + (idx & 63)] = tp[idx];
    }
    __syncthreads();
    const int l  = t & 63;                 // lane = l -> coalesced bf16 row writes
    const int o0 = (t >> 6) * 16;
    float acc[16];
    #pragma unroll
    for (int i = 0; i < 16; ++i) acc[i] = 0.f;
    for (int f = 0; f < 64; ++f) {
        float tv = st[l * 65 + f];
        #pragma unroll
        for (int i = 0; i < 16; ++i) acc[i] += tv * sw[f * 64 + o0 + i];
    }
    unsigned short* hp = hT + ((size_t)b * FDIM + o0) * LDIM + l0 + l;
    #pragma unroll
    for (int i = 0; i < 16; ++i) hp[(size_t)i * LDIM] = f2bf(acc[i]);
}

// Kernel 2: out[b] = adj[b] @ hidden[b] + bias.  M=4096 N=64 K=4096 per batch.
// BM=64, full N=64, BK=64; 4 waves, each: 16 M-rows x 64 N-cols (1x4 16x16x32 frags).
__global__ __launch_bounds__(256, 2) void gemm_kernel(
    const float* __restrict__ adj, const unsigned short* __restrict__ hT,
    const float* __restrict__ bias, float* __restrict__ out)
{
    const int b  = blockIdx.x & 7;         // batch -> XCD affinity (hidden[b] L2-resident)
    const int mb = blockIdx.x >> 3;        // 0..63
    const int m0 = mb * BM;
    const int tid  = threadIdx.x;
    const int w    = tid >> 6;
    const int lane = tid & 63;

    // +8 bf16 pad per row (144B stride): fragment reads land 2-way max (free)
    __shared__ __align__(16) unsigned short sA[BM * 72];   // A[m][k] bf16
    __shared__ __align__(16) unsigned short sB[64 * 72];   // B stored [n][k] bf16

    const float*          abase = adj + ((size_t)b * LDIM + m0) * LDIM;
    const unsigned short* hbase = hT + (size_t)b * FDIM * LDIM;

    const int am = tid >> 4;   // A load: row base (+16*i), 0..15
    const int ac = tid & 15;   // A load: 4-float col group
    const int bn = tid >> 3;   // B load: n base (+32*i), 0..31
    const int bg = tid & 7;    // B load: 8-bf16 k group

    float4 aCur[4]; uint4 bCur[2];
    #pragma unroll
    for (int i = 0; i < 4; ++i)
        aCur[i] = *(const float4*)(abase + (size_t)(am + 16 * i) * LDIM + ac * 4);
    #pragma unroll
    for (int i = 0; i < 2; ++i)
        bCur[i] = *(const uint4*)(hbase + (size_t)(bn + 32 * i) * LDIM + bg * 8);

    f32x4 acc[4];
    #pragma unroll
    for (int nf = 0; nf < 4; ++nf) acc[nf] = (f32x4){0.f, 0.f, 0.f, 0.f};

    const int fm = lane & 15;
    const int fq = lane >> 4;

    for (int it = 0; it < NIT; ++it) {
        __syncthreads();                   // prev iter's frag reads done
        #pragma unroll
        for (int i = 0; i < 4; ++i) {
            union { unsigned short us[4]; uint2 v; } pk;
            pk.us[0] = f2bf(aCur[i].x); pk.us[1] = f2bf(aCur[i].y);
            pk.us[2] = f2bf(aCur[i].z); pk.us[3] = f2bf(aCur[i].w);
            *(uint2*)&sA[(am + 16 * i) * 72 + ac * 4] = pk.v;
        }
        #pragma unroll
        for (int i = 0; i < 2; ++i)
            *(uint4*)&sB[(bn + 32 * i) * 72 + bg * 8] = bCur[i];
        __syncthreads();

        // prefetch next K-tile into registers (overlaps ds_read + MFMA below)
        float4 aNxt[4]; uint4 bNxt[2];
        const int nk = (it + 1) * BK;
        const bool more = (it + 1 < NIT);
        if (more) {
            #pragma unroll
            for (int i = 0; i < 4; ++i)
                aNxt[i] = *(const float4*)(abase + (size_t)(am + 16 * i) * LDIM + nk + ac * 4);
            #pragma unroll
            for (int i = 0; i < 2; ++i)
                bNxt[i] = *(const uint4*)(hbase + (size_t)(bn + 32 * i) * LDIM + nk + bg * 8);
        }

        #pragma unroll
        for (int kf = 0; kf < 2; ++kf) {
            bf16x8 af = *(const bf16x8*)&sA[(w * 16 + fm) * 72 + kf * 32 + fq * 8];
            #pragma unroll
            for (int nf = 0; nf < 4; ++nf) {
                bf16x8 bfr = *(const bf16x8*)&sB[(nf * 16 + fm) * 72 + kf * 32 + fq * 8];
                acc[nf] = __builtin_amdgcn_mfma_f32_16x16x32_bf16(af, bfr, acc[nf], 0, 0, 0);
            }
        }

        if (more) {
            #pragma unroll
            for (int i = 0; i < 4; ++i) aCur[i] = aNxt[i];
            #pragma unroll
            for (int i = 0; i < 2; ++i) bCur[i] = bNxt[i];
        }
    }

    // epilogue: C/D layout col = lane&15, row = (lane>>4)*4 + reg
    float* obase = out + ((size_t)b * LDIM + m0 + w * 16 + fq * 4) * FDIM + fm;
    #pragma unroll
    for (int nf = 0; nf < 4; ++nf) {
        float bv = bias[nf * 16 + fm];
        #pragma unroll
        for (int r = 0; r < 4; ++r)
            obase[(size_t)r * FDIM + nf * 16] = acc[nf][r] + bv;
    }
}

extern "C" void kernel_launch(void* const* d_in, const int* in_sizes, int n_in,
                              void* d_out, int out_size, void* d_ws, size_t ws_size,
                              hipStream_t stream) {
    const float* text   = (const float*)d_in[0];
    const float* adj    = (const float*)d_in[1];
    const float* weight = (const float*)d_in[2];
    const float* bias   = (const float*)d_in[3];
    float* out = (float*)d_out;
    unsigned short* hT = (unsigned short*)d_ws;   // 8*64*4096*2 = 4 MB

    hidden_kernel<<<512, 256, 0, stream>>>(text, weight, hT);
    gemm_kernel<<<512, 256, 0, stream>>>(adj, hT, bias, out);
}